// Round 3
// baseline (521.418 us; speedup 1.0000x reference)
//
#include <hip/hip_runtime.h>
#include <stdint.h>

// DenseGGNN on MI355X, round 12.
//  - adj is binary -> adjT stored as PACKED BITMASK adjB (4.2 MB total, L2-resident)
//    instead of 67 MB bf16. k_mega6 expands bits -> bf16 {0, 0x3F80} directly into
//    the swizzled LDS A-tile (replaces 2 glds16/thread/chunk of HBM traffic with an
//    L2-hot u16 load + ~30 VALU + 2 ds_write_b128, overlapped with MFMA).
//    Saves 67 MB of k_setup writes + 67 MB/layer of k_mega6 HBM staging.
//    GEMM operand bits identical to rounds 9-11 -> absmax unchanged.
//  - k_setup: phase A per-lane bitmask build (coalesced f32x4 reads) -> LDS mask
//    redistribute -> one dwordx4 mask store per row. k_hw unchanged.

#define NB 32
#define NN 1024
#define NC 128
#define NL 4
#define MTOT (NB * NN)   // 32768

#define KT 64
#define PITCH 72         // k_hw LDS pitch
#define MP 136           // m-LDS pitch (U16): row stride 272B -> bank step 4, <=2-way reads
#define MSKP 260         // mask LDS pitch (u32 words) per j-block

typedef __attribute__((ext_vector_type(8))) short s16x8;
typedef __attribute__((ext_vector_type(4))) float f32x4;
typedef __attribute__((ext_vector_type(2))) unsigned int u32x2;
typedef __attribute__((ext_vector_type(4))) unsigned int u32x4;
typedef unsigned short U16;
typedef unsigned int U32;

__device__ __forceinline__ U16 f2bf(float f) {
    union { float f; U32 u; } v; v.f = f;
    return (U16)((v.u + 0x7FFFu + ((v.u >> 16) & 1u)) >> 16);  // RNE
}
__device__ __forceinline__ float bf2f(U16 h) {
    union { U32 u; float f; } v; v.u = ((U32)h) << 16;
    return v.f;
}
__device__ __forceinline__ void splitbf(float x, U16& hi, U16& lo) {
    hi = f2bf(x);
    lo = f2bf(x - bf2f(hi));
}
__device__ __forceinline__ float sigmoidf_(float x) { return 1.f / (1.f + __expf(-x)); }

__device__ __forceinline__ void glds16(const void* g, void* l) {
    __builtin_amdgcn_global_load_lds(
        (const __attribute__((address_space(1))) void*)g,
        (__attribute__((address_space(3))) void*)l, 16, 0, 0);
}

// swizzled LDS offset: row stride 64 U16, k-group g XORed with row&7
#define SWZ(row, g) ((row) * 64 + ((((g) ^ ((row) & 7))) * 8))

// ---------------- setup: adj -> bitmask adjB + weight split + h init ----------------
// grid: [0,1024)    adj bitmask: 32 b x 4 n-slabs(256) x 8 j-slabs(128)
//       [1024,2816) weight split (458752 elements)
//       [2816,3840) h init (4.19M elements, 4096/block)
// adjB layout: [b][n][64 u16] = 1024 j-bits per row (bit j of row n = adj[b][j][n]!=0)
__global__ __launch_bounds__(256) void k_setup(
    const float* __restrict__ adj, U16* __restrict__ adjB,
    const float* __restrict__ w, const float* __restrict__ wih, const float* __restrict__ whh,
    U16* __restrict__ wThi, U16* __restrict__ wTlo,
    U16* __restrict__ wihhi, U16* __restrict__ wihlo,
    U16* __restrict__ whhhi, U16* __restrict__ whhlo,
    const float* __restrict__ x, U16* __restrict__ hhi, U16* __restrict__ hlo)
{
    __shared__ U32 msk[4 * MSKP];                  // [j-word 0..3][n_local 0..255]
    const int bid = blockIdx.x, tid = threadIdx.x;
    if (bid < 1024) {                              // adj fp32 [b][j][n] -> adjB bits [b][n][j]
        const int b = bid >> 5, rem = bid & 31;
        const int n0 = (rem >> 3) * 256;           // 256-wide n slab
        const int j0 = (rem & 7) * 128;            // 128-wide j slab
        const int lane = tid & 63, wv = tid >> 6;
        const int jb = j0 + wv * 32;               // this wave's 32 consecutive j
        const int nl = n0 + lane * 4;              // this lane's 4 consecutive n

        // phase A: coalesced reads, transpose-in-register as bitmasks
        U32 mk0 = 0, mk1 = 0, mk2 = 0, mk3 = 0;
#pragma unroll 8
        for (int jj = 0; jj < 32; ++jj) {
            f32x4 v = *(const f32x4*)&adj[((size_t)b << 20) + ((size_t)(jb + jj) << 10) + nl];
            U32 bit = 1u << jj;
            if (v[0] != 0.f) mk0 |= bit;
            if (v[1] != 0.f) mk1 |= bit;
            if (v[2] != 0.f) mk2 |= bit;
            if (v[3] != 0.f) mk3 |= bit;
        }
        u32x4 mv; mv[0] = mk0; mv[1] = mk1; mv[2] = mk2; mv[3] = mk3;
        *(u32x4*)&msk[wv * MSKP + lane * 4] = mv;  // [j-word wv][rows nl..nl+3]
        __syncthreads();

        // phase B: one row per thread, pack 4 j-words, single dwordx4 store
        u32x4 wd;
        wd[0] = msk[0 * MSKP + tid];
        wd[1] = msk[1 * MSKP + tid];
        wd[2] = msk[2 * MSKP + tid];
        wd[3] = msk[3 * MSKP + tid];
        *(u32x4*)&adjB[(((size_t)b << 10) + n0 + tid) * 64 + (rem & 7) * 8] = wd;
    } else if (bid < 2816) {                       // weight split (458752 elements)
        int i = (bid - 1024) * 256 + tid;
        if (i < 65536) {                           // weight [L][C][C] -> wT [L][d][c]
            int l = i >> 14, rem = i & 16383, c = rem >> 7, d = rem & 127;
            U16 hi, lo; splitbf(w[i], hi, lo);
            int o = (l << 14) + (d << 7) + c;
            wThi[o] = hi; wTlo[o] = lo;
        } else if (i < 262144) {
            int j = i - 65536;
            U16 hi, lo; splitbf(wih[j], hi, lo);
            wihhi[j] = hi; wihlo[j] = lo;
        } else {
            int j = i - 262144;
            U16 hi, lo; splitbf(whh[j], hi, lo);
            whhhi[j] = hi; whhlo[j] = lo;
        }
    } else {                                       // h init from x (4.19M elements, vectorized)
        const int base = (bid - 2816) * 4096;
#pragma unroll
        for (int g = 0; g < 4; ++g) {
            int i = base + (g * 256 + tid) * 4;
            f32x4 v = *(const f32x4*)&x[i];
            U16 h0, l0, h1, l1, h2, l2, h3, l3;
            splitbf(v[0], h0, l0); splitbf(v[1], h1, l1);
            splitbf(v[2], h2, l2); splitbf(v[3], h3, l3);
            u32x2 ph, pl;
            ph[0] = (U32)h0 | ((U32)h1 << 16); ph[1] = (U32)h2 | ((U32)h3 << 16);
            pl[0] = (U32)l0 | ((U32)l1 << 16); pl[1] = (U32)l2 | ((U32)l3 << 16);
            *(u32x2*)&hhi[i] = ph;
            *(u32x2*)&hlo[i] = pl;
        }
    }
}

// ---------------- K1: hw = h @ W (3-product), writes hwT[b][d][j] hi/lo ----------------
struct __align__(16) Smem3 {
    union {
        struct { U16 A[2][128 * PITCH]; U16 B[2][128 * PITCH]; } s;   // 73728 B
        float bounce[128 * 129];                                      // 66048 B
    };
};

__global__ __launch_bounds__(256, 2) void k_hw(
    const U16* __restrict__ Ahi, const U16* __restrict__ Alo,
    const U16* __restrict__ Bhi, const U16* __restrict__ Blo,
    U16* __restrict__ Ohi, U16* __restrict__ Olo)
{
    __shared__ Smem3 sm;
    const int tid = threadIdx.x;
    const int lane = tid & 63, wv = tid >> 6;
    const int wr = (wv & 1) * 64, wc = (wv >> 1) * 64;
    const int lm = lane & 15, lk8 = (lane >> 4) * 8;
    const int m0 = blockIdx.x * 128;

    f32x4 acc[4][4] = {};

    for (int kc = 0; kc < 128; kc += KT) {
#pragma unroll
        for (int t = 0; t < 4; ++t) {
            int i = tid + t * 256; int r = i >> 3, v = (i & 7) * 8;
            *(s16x8*)&sm.s.A[0][r * PITCH + v] = *(const s16x8*)&Ahi[(size_t)(m0 + r) * 128 + kc + v];
            *(s16x8*)&sm.s.A[1][r * PITCH + v] = *(const s16x8*)&Alo[(size_t)(m0 + r) * 128 + kc + v];
        }
#pragma unroll
        for (int t = 0; t < 4; ++t) {
            int i = tid + t * 256; int r = i >> 3, v = (i & 7) * 8;
            *(s16x8*)&sm.s.B[0][r * PITCH + v] = *(const s16x8*)&Bhi[r * 128 + kc + v];
            *(s16x8*)&sm.s.B[1][r * PITCH + v] = *(const s16x8*)&Blo[r * 128 + kc + v];
        }
        __syncthreads();
#pragma unroll
        for (int ks = 0; ks < 2; ++ks) {
            const int ko = ks * 32 + lk8;
            s16x8 ahi[4], alo[4], bhi[4], blo[4];
#pragma unroll
            for (int q = 0; q < 4; ++q) {
                ahi[q] = *(const s16x8*)&sm.s.A[0][(wr + q * 16 + lm) * PITCH + ko];
                alo[q] = *(const s16x8*)&sm.s.A[1][(wr + q * 16 + lm) * PITCH + ko];
                bhi[q] = *(const s16x8*)&sm.s.B[0][(wc + q * 16 + lm) * PITCH + ko];
                blo[q] = *(const s16x8*)&sm.s.B[1][(wc + q * 16 + lm) * PITCH + ko];
            }
#pragma unroll
            for (int rt = 0; rt < 4; ++rt)
#pragma unroll
                for (int ct = 0; ct < 4; ++ct) {
                    f32x4 a = acc[rt][ct];
                    a = __builtin_amdgcn_mfma_f32_16x16x32_bf16(ahi[rt], bhi[ct], a, 0, 0, 0);
                    a = __builtin_amdgcn_mfma_f32_16x16x32_bf16(ahi[rt], blo[ct], a, 0, 0, 0);
                    a = __builtin_amdgcn_mfma_f32_16x16x32_bf16(alo[rt], bhi[ct], a, 0, 0, 0);
                    acc[rt][ct] = a;
                }
        }
        __syncthreads();
    }
#pragma unroll
    for (int rt = 0; rt < 4; ++rt)
#pragma unroll
        for (int ct = 0; ct < 4; ++ct)
#pragma unroll
            for (int r = 0; r < 4; ++r)
                sm.bounce[(wr + rt * 16 + (lane >> 4) * 4 + r) * 129 + wc + ct * 16 + lm] = acc[rt][ct][r];
    __syncthreads();
    const int b = m0 >> 10, j0 = m0 & 1023;
    for (int t = 0; t < 32; ++t) {
        int i = tid + t * 256; int d = i >> 6, j2 = (i & 63) * 2;
        float x0 = sm.bounce[j2 * 129 + d], x1 = sm.bounce[(j2 + 1) * 129 + d];
        U16 h0, l0, h1, l1; splitbf(x0, h0, l0); splitbf(x1, h1, l1);
        size_t o = (((size_t)(b * 128 + d)) << 10) + j0 + j2;
        *(U32*)&Ohi[o] = (U32)h0 | ((U32)h1 << 16);
        *(U32*)&Olo[o] = (U32)l0 | ((U32)l1 << 16);
    }
}

// ---------------- k_mega7: bit-expand A-tile + hw staging -> m in LDS -> gates -> GRU ----------------
__global__ __launch_bounds__(256, 2) void k_mega7(
    const U16* __restrict__ adjB,                                 // [NB][NN][64] bit rows
    const U16* __restrict__ hwThi, const U16* __restrict__ hwTlo, // [NB][128][1024]
    const U16* __restrict__ hhi, const U16* __restrict__ hlo,     // [MTOT][128]
    const U16* __restrict__ wihhi, const U16* __restrict__ wihlo, // [384][128] layer slice
    const U16* __restrict__ whhhi, const U16* __restrict__ whhlo,
    const float* __restrict__ bih, const float* __restrict__ bhh, // [384] layer slice
    const float* __restrict__ mask,
    U16* __restrict__ houthi, U16* __restrict__ houtlo,
    float* __restrict__ out, int last)
{
    __shared__ __align__(16) union {
        struct { U16 As[2][64 * 64]; U16 Bh[2][128 * 64]; U16 Bl[2][128 * 64]; } st; // 81920 B
        struct { U16 Mhi[64 * MP]; U16 Mlo[64 * MP]; } m;                            // 34816 B
    } u;
    const int tid = threadIdx.x;
    const int lane = tid & 63, wv = tid >> 6;
    const int wd0 = wv * 32;                       // wave's 32-col slice
    const int lm = lane & 15, lk8 = (lane >> 4) * 8, quad = lane >> 4;
    const int xcd = blockIdx.x & 7;
    const int j = blockIdx.x >> 3;                 // 0..63
    const int bt = xcd * 4 + (j >> 4);
    const int n0 = (j & 15) * 64;
    const int row0 = bt * NN + n0;

    // ---- A-expansion thread mapping (loop-invariant) ----
    // thread handles row er (0..63), LDS slots {2*ea2, 2*ea2+1}; slot s holds
    // byte (s ^ (er&7)) of the 8-byte chunk window (matches reader SWZ).
    const int er  = tid >> 2;
    const int ea  = tid & 3;
    const int ex  = er & 7;
    const int ea2 = ea ^ (er & 3);
    const int eB0h = (2 * (ea2 ^ (ex >> 1))) >> 1;     // u16 index of byte pair in window
    const int es1 = 2 * ea2 + (er & 1);                // write order: spread banks 8-way
    const int es2 = 2 * ea2 + 1 - (er & 1);
    const int esh1 = 8 * ((es1 ^ ex) & 1);             // lo/hi byte shift for slot es1
    const int esh2 = 8 * ((es2 ^ ex) & 1);
    const U16* __restrict__ mrow = adjB + (((size_t)bt << 10) + n0 + er) * 64;

#define EXPA(c, b)                                                                        \
    {                                                                                     \
        U32 v = mrow[(c) * 4 + eB0h];                                                     \
        U32 by1 = (v >> esh1) & 0xffu;                                                    \
        U32 by2 = (v >> esh2) & 0xffu;                                                    \
        u32x4 w1, w2;                                                                     \
        _Pragma("unroll")                                                                 \
        for (int i = 0; i < 4; ++i) {                                                     \
            w1[i] = (((by1 >> (2 * i)) & 1u) ? 0x00003F80u : 0u)                          \
                  | (((by1 >> (2 * i + 1)) & 1u) ? 0x3F800000u : 0u);                     \
            w2[i] = (((by2 >> (2 * i)) & 1u) ? 0x00003F80u : 0u)                          \
                  | (((by2 >> (2 * i + 1)) & 1u) ? 0x3F800000u : 0u);                     \
        }                                                                                 \
        *(u32x4*)&u.st.As[b][er * 64 + es1 * 8] = w1;                                     \
        *(u32x4*)&u.st.As[b][er * 64 + es2 * 8] = w2;                                     \
    }

#define STAGE_B(kc, b)                                                                    \
    {                                                                                     \
        _Pragma("unroll")                                                                 \
        for (int t = 0; t < 4; ++t) {                                                     \
            int li = tid + t * 256; int d = li >> 3, sg = li & 7;                         \
            size_t o = (((size_t)(bt * 128 + d)) << 10) + (kc) + ((sg ^ (d & 7)) * 8);    \
            glds16(&hwThi[o], &u.st.Bh[b][li * 8]);                                       \
            glds16(&hwTlo[o], &u.st.Bl[b][li * 8]);                                       \
        }                                                                                 \
    }

    // ---- phase 1: m = adjB-expand @ hw (2-product), dbuf pipeline ----
    f32x4 macc[4][2] = {};
    STAGE_B(0, 0);
    EXPA(0, 0);
    for (int c = 0; c < 16; ++c) {
        const int b = c & 1;
        __syncthreads();                           // buf b ready (vmcnt+lgkmcnt drained)
        if (c + 1 < 16) {
            STAGE_B((c + 1) * 64, b ^ 1);          // hw prefetch, in flight during compute
            EXPA(c + 1, b ^ 1);                    // bit-expand next A-tile (L2-hot u16)
        }
#pragma unroll
        for (int ks = 0; ks < 2; ++ks) {
            const int g = ks * 4 + quad;           // k-group 0..7
            s16x8 a[4], bh[2], bl[2];
#pragma unroll
            for (int q = 0; q < 4; ++q)
                a[q] = *(const s16x8*)&u.st.As[b][SWZ(q * 16 + lm, g)];
#pragma unroll
            for (int q = 0; q < 2; ++q) {
                bh[q] = *(const s16x8*)&u.st.Bh[b][SWZ(wd0 + q * 16 + lm, g)];
                bl[q] = *(const s16x8*)&u.st.Bl[b][SWZ(wd0 + q * 16 + lm, g)];
            }
#pragma unroll
            for (int rt = 0; rt < 4; ++rt)
#pragma unroll
                for (int ct = 0; ct < 2; ++ct) {
                    f32x4 cc = macc[rt][ct];
                    cc = __builtin_amdgcn_mfma_f32_16x16x32_bf16(a[rt], bh[ct], cc, 0, 0, 0);
                    cc = __builtin_amdgcn_mfma_f32_16x16x32_bf16(a[rt], bl[ct], cc, 0, 0, 0);
                    macc[rt][ct] = cc;
                }
        }
    }
#undef STAGE_B
#undef EXPA
    __syncthreads();                               // all waves done reading staging LDS

    // ---- m -> LDS hi/lo (union overwrites staging; bit-identical split values) ----
#pragma unroll
    for (int rt = 0; rt < 4; ++rt)
#pragma unroll
        for (int ct = 0; ct < 2; ++ct)
#pragma unroll
            for (int rr = 0; rr < 4; ++rr) {
                int rloc = rt * 16 + quad * 4 + rr;
                int d = wd0 + ct * 16 + lm;
                U16 hi, lo; splitbf(macc[rt][ct][rr], hi, lo);
                u.m.Mhi[rloc * MP + d] = hi;
                u.m.Mlo[rloc * MP + d] = lo;
            }
    // no barrier yet — h-chunks (no m dependency) run first; barrier before m-chunks

    // ---- phase 2: gates (K=256 concat [m|h], 3-product) + GRU ----
    f32x4 aR[4][2], aZ[4][2], aXN[4][2], aHN[4][2];
#pragma unroll
    for (int ct = 0; ct < 2; ++ct) {
        const int col = wd0 + ct * 16 + lm;
        const float bR  = bih[col]       + bhh[col];
        const float bZ  = bih[128 + col] + bhh[128 + col];
        const float bXN = bih[256 + col];
        const float bHN = bhh[256 + col];
#pragma unroll
        for (int rt = 0; rt < 4; ++rt) {
            aR[rt][ct]  = f32x4{bR, bR, bR, bR};
            aZ[rt][ct]  = f32x4{bZ, bZ, bZ, bZ};
            aXN[rt][ct] = f32x4{bXN, bXN, bXN, bXN};
            aHN[rt][ct] = f32x4{bHN, bHN, bHN, bHN};
        }
    }

    for (int cc = 0; cc < 4; ++cc) {
        const int ch = (cc + 2) & 3;               // order: 2,3 (h, global) then 0,1 (m, LDS)
        if (cc == 2) __syncthreads();              // m ds_writes complete + visible block-wide
        const U16* __restrict__ Whi = (ch < 2) ? wihhi : whhhi;
        const U16* __restrict__ Wlo = (ch < 2) ? wihlo : whhlo;
        const int kb = (ch & 1) * 64;
#pragma unroll
        for (int ks = 0; ks < 2; ++ks) {
            const int ko = kb + ks * 32 + lk8;     // k within [0,128)
            s16x8 ahi[4], alo[4];
            if (ch < 2) {
#pragma unroll
                for (int q = 0; q < 4; ++q) {
                    ahi[q] = *(const s16x8*)&u.m.Mhi[(q * 16 + lm) * MP + ko];
                    alo[q] = *(const s16x8*)&u.m.Mlo[(q * 16 + lm) * MP + ko];
                }
            } else {
#pragma unroll
                for (int q = 0; q < 4; ++q) {
                    size_t ao = (size_t)(row0 + q * 16 + lm) * 128 + ko;
                    ahi[q] = *(const s16x8*)&hhi[ao];
                    alo[q] = *(const s16x8*)&hlo[ao];
                }
            }
#pragma unroll
            for (int ct = 0; ct < 2; ++ct) {
                const int col = wd0 + ct * 16 + lm;
                s16x8 bhiR = *(const s16x8*)&Whi[(size_t)col * 128 + ko];
                s16x8 bloR = *(const s16x8*)&Wlo[(size_t)col * 128 + ko];
                s16x8 bhiZ = *(const s16x8*)&Whi[(size_t)(128 + col) * 128 + ko];
                s16x8 bloZ = *(const s16x8*)&Wlo[(size_t)(128 + col) * 128 + ko];
                s16x8 bhiN = *(const s16x8*)&Whi[(size_t)(256 + col) * 128 + ko];
                s16x8 bloN = *(const s16x8*)&Wlo[(size_t)(256 + col) * 128 + ko];
#pragma unroll
                for (int rt = 0; rt < 4; ++rt) {
                    f32x4 r = aR[rt][ct];
                    r = __builtin_amdgcn_mfma_f32_16x16x32_bf16(ahi[rt], bhiR, r, 0, 0, 0);
                    r = __builtin_amdgcn_mfma_f32_16x16x32_bf16(ahi[rt], bloR, r, 0, 0, 0);
                    r = __builtin_amdgcn_mfma_f32_16x16x32_bf16(alo[rt], bhiR, r, 0, 0, 0);
                    aR[rt][ct] = r;
                    f32x4 z = aZ[rt][ct];
                    z = __builtin_amdgcn_mfma_f32_16x16x32_bf16(ahi[rt], bhiZ, z, 0, 0, 0);
                    z = __builtin_amdgcn_mfma_f32_16x16x32_bf16(ahi[rt], bloZ, z, 0, 0, 0);
                    z = __builtin_amdgcn_mfma_f32_16x16x32_bf16(alo[rt], bhiZ, z, 0, 0, 0);
                    aZ[rt][ct] = z;
                }
                if (ch < 2) {
#pragma unroll
                    for (int rt = 0; rt < 4; ++rt) {
                        f32x4 n = aXN[rt][ct];
                        n = __builtin_amdgcn_mfma_f32_16x16x32_bf16(ahi[rt], bhiN, n, 0, 0, 0);
                        n = __builtin_amdgcn_mfma_f32_16x16x32_bf16(ahi[rt], bloN, n, 0, 0, 0);
                        n = __builtin_amdgcn_mfma_f32_16x16x32_bf16(alo[rt], bhiN, n, 0, 0, 0);
                        aXN[rt][ct] = n;
                    }
                } else {
#pragma unroll
                    for (int rt = 0; rt < 4; ++rt) {
                        f32x4 n = aHN[rt][ct];
                        n = __builtin_amdgcn_mfma_f32_16x16x32_bf16(ahi[rt], bhiN, n, 0, 0, 0);
                        n = __builtin_amdgcn_mfma_f32_16x16x32_bf16(ahi[rt], bloN, n, 0, 0, 0);
                        n = __builtin_amdgcn_mfma_f32_16x16x32_bf16(alo[rt], bhiN, n, 0, 0, 0);
                        aHN[rt][ct] = n;
                    }
                }
            }
        }
    }

    // ---- GRU epilogue; h re-read from global; in-place h update ----
#pragma unroll
    for (int rt = 0; rt < 4; ++rt) {
#pragma unroll
        for (int ct = 0; ct < 2; ++ct) {
            const int col = wd0 + ct * 16 + lm;
#pragma unroll
            for (int rr = 0; rr < 4; ++rr) {
                const int row = row0 + rt * 16 + quad * 4 + rr;
                float r = sigmoidf_(aR[rt][ct][rr]);
                float z = sigmoidf_(aZ[rt][ct][rr]);
                float n = tanhf(aXN[rt][ct][rr] + r * aHN[rt][ct][rr]);
                size_t ho = (size_t)row * 128 + col;
                float hv = bf2f(hhi[ho]) + bf2f(hlo[ho]);
                float hnew = (1.f - z) * n + z * hv;
                if (last) {
                    out[ho] = hnew * mask[row];
                } else {
                    U16 hi2, lo2; splitbf(hnew, hi2, lo2);
                    houthi[ho] = hi2;
                    houtlo[ho] = lo2;
                }
            }
        }
    }
}

// ---------------- launch ----------------
extern "C" void kernel_launch(void* const* d_in, const int* in_sizes, int n_in,
                              void* d_out, int out_size, void* d_ws, size_t ws_size,
                              hipStream_t stream) {
    (void)in_sizes; (void)n_in; (void)out_size; (void)ws_size;
    const float* x    = (const float*)d_in[0];
    const float* adj  = (const float*)d_in[1];
    const float* mask = (const float*)d_in[2];
    const float* wgt  = (const float*)d_in[3];
    const float* wih  = (const float*)d_in[4];
    const float* whh  = (const float*)d_in[5];
    const float* bih  = (const float*)d_in[6];
    const float* bhh  = (const float*)d_in[7];
    float* out = (float*)d_out;

    char* p = (char*)d_ws;
    U16* adjB    = (U16*)p;                p += (size_t)NB * NN * 64 * 2;   // 4.2 MB bitmask
    U16* h_hi    = (U16*)p;                p += (size_t)MTOT * NC * 2;
    U16* h_lo    = (U16*)p;                p += (size_t)MTOT * NC * 2;
    U16* hwT_hi  = (U16*)p;                p += (size_t)NB * NC * NN * 2;
    U16* hwT_lo  = (U16*)p;                p += (size_t)NB * NC * NN * 2;
    U16* wT_hi   = (U16*)p;                p += (size_t)NL * NC * NC * 2;
    U16* wT_lo   = (U16*)p;                p += (size_t)NL * NC * NC * 2;
    U16* wih_hi  = (U16*)p;                p += (size_t)NL * 384 * NC * 2;
    U16* wih_lo  = (U16*)p;                p += (size_t)NL * 384 * NC * 2;
    U16* whh_hi  = (U16*)p;                p += (size_t)NL * 384 * NC * 2;
    U16* whh_lo  = (U16*)p;                p += (size_t)NL * 384 * NC * 2;

    k_setup<<<3840, 256, 0, stream>>>(adj, adjB, wgt, wih, whh,
                                      wT_hi, wT_lo, wih_hi, wih_lo, whh_hi, whh_lo,
                                      x, h_hi, h_lo);

    for (int l = 0; l < NL; ++l) {
        k_hw<<<256, 256, 0, stream>>>(h_hi, h_lo,
                                      wT_hi + l * 16384, wT_lo + l * 16384,
                                      hwT_hi, hwT_lo);
        k_mega7<<<512, 256, 0, stream>>>(adjB, hwT_hi, hwT_lo, h_hi, h_lo,
                                         wih_hi + l * 49152, wih_lo + l * 49152,
                                         whh_hi + l * 49152, whh_lo + l * 49152,
                                         bih + l * 384, bhh + l * 384, mask,
                                         h_hi, h_lo, out, (l == NL - 1) ? 1 : 0);
    }
}